// Round 3
// baseline (757.808 us; speedup 1.0000x reference)
//
#include <hip/hip_runtime.h>
#include <stdint.h>

typedef unsigned short u16;
typedef short short8 __attribute__((ext_vector_type(8)));
typedef short short4v __attribute__((ext_vector_type(4)));
typedef float floatx4 __attribute__((ext_vector_type(4)));

#define S_LEN 2048
#define NB 2
#define NH 8
#define R_TOK (NB * S_LEN)  // 4096

// log2(10000)
#define L2_THETA 13.287712379549449f
// attention scale folded into Q, in log2 domain: (1/sqrt(128)) * log2(e)
#define QSCALE (0.08838834764831845f * 1.4426950408889634f)

__device__ inline u16 f2bf(float f) {
  union { float f; uint32_t u; } x; x.f = f;
  uint32_t r = (x.u + 0x7fffu + ((x.u >> 16) & 1u)) >> 16;
  return (u16)r;
}
__device__ inline float bf2f(u16 h) {
  union { uint32_t u; float f; } x; x.u = ((uint32_t)h) << 16;
  return x.f;
}
__device__ inline floatx4 mfma16(short8 a, short8 b, floatx4 c) {
  return __builtin_amdgcn_mfma_f32_16x16x32_bf16(a, b, c, 0, 0, 0);
}

// ---------------- fp32 -> bf16 convert (vectorized) ----------------
__global__ void k_f2bf(const float* __restrict__ in, u16* __restrict__ out, int n4) {
  int i = blockIdx.x * blockDim.x + threadIdx.x;
  if (i < n4) {
    float4 v = ((const float4*)in)[i];
    ushort4 o;
    o.x = f2bf(v.x); o.y = f2bf(v.y); o.z = f2bf(v.z); o.w = f2bf(v.w);
    ((ushort4*)out)[i] = o;
  }
}

// ---------------- tiled fp32 [R][C] -> bf16 transpose [C][R] ----------------
__global__ void k_tbf(const float* __restrict__ in, u16* __restrict__ out, int R, int C) {
  __shared__ u16 t[32][33];
  int c0 = blockIdx.x * 32, r0 = blockIdx.y * 32;
  int tx = threadIdx.x, ty = threadIdx.y;  // 32 x 8
#pragma unroll
  for (int i = 0; i < 4; ++i)
    t[ty + i * 8][tx] = f2bf(in[(size_t)(r0 + ty + i * 8) * C + c0 + tx]);
  __syncthreads();
#pragma unroll
  for (int i = 0; i < 4; ++i)
    out[(size_t)(c0 + ty + i * 8) * R + r0 + tx] = t[tx][ty + i * 8];
}

// concat-transpose: logical in = [1024][320] (wdq cols 0-127, wdkv cols 128-319) -> out [320][1024]
__global__ void k_tbf_wa(const float* __restrict__ wdq, const float* __restrict__ wdkv,
                         u16* __restrict__ out) {
  __shared__ u16 t[32][33];
  int c0 = blockIdx.x * 32, r0 = blockIdx.y * 32;
  int tx = threadIdx.x, ty = threadIdx.y;
#pragma unroll
  for (int i = 0; i < 4; ++i) {
    int r = r0 + ty + i * 8, c = c0 + tx;
    float v = (c < 128) ? wdq[(size_t)r * 128 + c] : wdkv[(size_t)r * 192 + (c - 128)];
    t[ty + i * 8][tx] = f2bf(v);
  }
  __syncthreads();
#pragma unroll
  for (int i = 0; i < 4; ++i)
    out[(size_t)(c0 + ty + i * 8) * 1024 + r0 + tx] = t[tx][ty + i * 8];
}

__global__ void k_biascat(const float* __restrict__ bdq, const float* __restrict__ bdkv,
                          float* __restrict__ biasA) {
  int i = blockIdx.x * 256 + threadIdx.x;
  if (i < 320) biasA[i] = (i < 128) ? bdq[i] : bdkv[i - 128];
}

// ---------------- 128x128-tile GEMM, B given transposed [N][K] ----------------
// C(MxN) = A(MxK) @ BT^T + bias. 4 waves, each 64x64 (4x4 16-tiles): 16 MFMA + 8 b128/step.
// stride-32 rows: b128 access pattern is 8 lanes per 4-dword bank group = optimal.
template <int OUT_BF>
__global__ __launch_bounds__(256) void k_gemm_bt(const u16* __restrict__ A,
                                                 const u16* __restrict__ BT,
                                                 const float* __restrict__ bias,
                                                 void* __restrict__ Cout,
                                                 int M, int N, int K) {
  __shared__ __align__(16) u16 Alds[128 * 32];
  __shared__ __align__(16) u16 Blds[128 * 32];
  const int tid = threadIdx.x;
  const int wave = tid >> 6, lane = tid & 63;
  const int lane15 = lane & 15, quad = lane >> 4;
  const int m0 = blockIdx.y * 128, n0 = blockIdx.x * 128;
  const int mw = (wave & 1) * 64, nw = (wave >> 1) * 64;

  floatx4 acc[4][4];
#pragma unroll
  for (int a = 0; a < 4; ++a)
#pragma unroll
    for (int b = 0; b < 4; ++b) acc[a][b] = (floatx4){0.f, 0.f, 0.f, 0.f};

  const int sr = tid >> 1, sh = (tid & 1) * 16;  // stage: 128 rows x 2 k-halves (16 hw)
  const bool bok = (n0 + sr) < N;

  for (int k0 = 0; k0 < K; k0 += 32) {
    __syncthreads();
    {
      const u16* s = A + (size_t)(m0 + sr) * K + k0 + sh;
      *(short8*)&Alds[sr * 32 + sh] = *(const short8*)s;
      *(short8*)&Alds[sr * 32 + sh + 8] = *(const short8*)(s + 8);
    }
    if (bok) {
      const u16* s = BT + (size_t)(n0 + sr) * K + k0 + sh;
      *(short8*)&Blds[sr * 32 + sh] = *(const short8*)s;
      *(short8*)&Blds[sr * 32 + sh + 8] = *(const short8*)(s + 8);
    }
    __syncthreads();
    short8 af[4], bf[4];
#pragma unroll
    for (int im = 0; im < 4; ++im)
      af[im] = *(const short8*)&Alds[(mw + im * 16 + lane15) * 32 + quad * 8];
#pragma unroll
    for (int in = 0; in < 4; ++in)
      bf[in] = *(const short8*)&Blds[(nw + in * 16 + lane15) * 32 + quad * 8];
#pragma unroll
    for (int im = 0; im < 4; ++im)
#pragma unroll
      for (int in = 0; in < 4; ++in) acc[im][in] = mfma16(af[im], bf[in], acc[im][in]);
  }

#pragma unroll
  for (int im = 0; im < 4; ++im)
#pragma unroll
    for (int in = 0; in < 4; ++in)
#pragma unroll
      for (int r = 0; r < 4; ++r) {
        int row = m0 + mw + im * 16 + quad * 4 + r;
        int col = n0 + nw + in * 16 + lane15;
        if (col < N) {
          float v = acc[im][in][r] + bias[col];
          if (OUT_BF)
            ((u16*)Cout)[(size_t)row * N + col] = f2bf(v);
          else
            ((float*)Cout)[(size_t)row * N + col] = v;
        }
      }
}

// ---------------- stage-A epilogue: rmsnorm(cq), rmsnorm(ckv), rope(k_rope) ----------------
__global__ void k_stagea(const float* __restrict__ t0, const float* __restrict__ qnw,
                         const float* __restrict__ kvnw, const int* __restrict__ pos_ids,
                         u16* __restrict__ cq, u16* __restrict__ ckv,
                         u16* __restrict__ krope) {
  int r = blockIdx.x, tid = threadIdx.x;  // 128 threads
  const float* row = t0 + (size_t)r * 320;
  float a = row[tid];
  float b = row[128 + tid];
  float sa = a * a, sb = b * b;
#pragma unroll
  for (int d = 1; d < 64; d <<= 1) {
    sa += __shfl_xor(sa, d);
    sb += __shfl_xor(sb, d);
  }
  __shared__ float red[4];
  if ((tid & 63) == 0) { red[(tid >> 6) * 2] = sa; red[(tid >> 6) * 2 + 1] = sb; }
  __syncthreads();
  sa = red[0] + red[2];
  sb = red[1] + red[3];
  float ra = rsqrtf(sa * (1.0f / 128.0f) + 1e-8f);
  float rb = rsqrtf(sb * (1.0f / 128.0f) + 1e-8f);
  cq[(size_t)r * 128 + tid] = f2bf(qnw[tid] * a * ra);
  ckv[(size_t)r * 128 + tid] = f2bf(kvnw[tid] * b * rb);
  if (tid < 32) {
    float xe = row[256 + 2 * tid], xo = row[256 + 2 * tid + 1];
    float p = (float)pos_ids[r];
    float freq = exp2f(-(2.0f * tid / 64.0f) * L2_THETA);
    float ang = p * freq;
    float c = cosf(ang), s = sinf(ang);
    krope[(size_t)r * 64 + 2 * tid] = f2bf(xe * c - xo * s);
    krope[(size_t)r * 64 + 2 * tid + 1] = f2bf(xe * s + xo * c);
  }
}

// ---------------- stage-B epilogue: rope(q_rope) + scale + scatter to (B,H,S,128) ----------------
__global__ void k_stageb(const u16* __restrict__ q, const int* __restrict__ pos_ids,
                         u16* __restrict__ qstates) {
  int r = blockIdx.x, tid = threadIdx.x;  // 256 threads
  int b = r >> 11, s = r & (S_LEN - 1);
  float p = (float)pos_ids[r];
#pragma unroll
  for (int i = 0; i < 4; ++i) {
    int idx = tid + i * 256;  // h*128 + d
    int h = idx >> 7, d = idx & 127;
    float val;
    if (d < 96) {
      val = bf2f(q[(size_t)r * 1024 + h * 96 + d]);
    } else {
      int j = d - 96, pr = j >> 1;
      float xe = bf2f(q[(size_t)r * 1024 + 768 + h * 32 + 2 * pr]);
      float xo = bf2f(q[(size_t)r * 1024 + 768 + h * 32 + 2 * pr + 1]);
      float freq = exp2f(-(2.0f * pr / 32.0f) * L2_THETA);
      float ang = p * freq;
      float c = cosf(ang), sn = sinf(ang);
      val = (j & 1) ? (xe * sn + xo * c) : (xe * c - xo * sn);
    }
    qstates[((size_t)(b * NH + h) * S_LEN + s) * 128 + d] = f2bf(val * QSCALE);
  }
}

// ---------------- flash attention, S^T formulation ----------------
// Block = (b,h) x 64 q-rows, 4 waves (16 q-rows each). K-chunk = 64.
// QK^T computed as S^T = K·Q^T: D gives lane q=lane15, k=quad*4+r -> P lands directly in
// MFMA-A operand order (no LDS round-trip). m/l are per-lane scalars; reduce = 2 shfl steps.
// PV: two 16-k tiles fused per full-rate 16x16x32 MFMA (b-frag = 2x b64 from V^T).
__device__ inline int kaddr(int row, int u) {
  return row * 128 + (((u & 8) | ((u ^ row) & 7)) << 3);
}
__device__ inline int vaddr(int n, int k) {  // k in [0,64); swizzle on 16B units
  return n * 64 + ((((k >> 3) ^ (n >> 3) ^ n) & 7) << 3) + (k & 7);
}

__global__ __launch_bounds__(256, 3) void k_attn(const u16* __restrict__ qstates,
                                                 const u16* __restrict__ kv,
                                                 const u16* __restrict__ krope,
                                                 u16* __restrict__ attn_out) {
  const int qblk = blockIdx.x;  // 0..31
  const int pair = blockIdx.y;  // 0..15
  const int b = pair >> 3, h = pair & 7;
  const int tid = threadIdx.x;
  const int wave = tid >> 6, lane = tid & 63;
  const int lane15 = lane & 15, quad = lane >> 4;

  __shared__ __align__(16) u16 Klds[64 * 128];  // 16 KB
  __shared__ __align__(16) u16 Vlds[256 * 64];  // 32 KB

  const int qrow0 = qblk * 64 + wave * 16;
  short8 qfrag[4];
  {
    const u16* qb = qstates + ((size_t)(b * NH + h) * S_LEN + qrow0 + lane15) * 128 + quad * 8;
#pragma unroll
    for (int c = 0; c < 4; ++c) qfrag[c] = *(const short8*)(qb + c * 32);
  }

  floatx4 o_acc[16];
#pragma unroll
  for (int g = 0; g < 16; ++g) o_acc[g] = (floatx4){0.f, 0.f, 0.f, 0.f};
  float m_i = -1e30f, l_i = 0.f;  // per-lane: q-row = lane15 (replicated across quads)

  const int kr = tid >> 2, q4 = tid & 3;           // K: 64 rows x 4 quarters
  const int vn8 = (tid & 31) * 8, vkb = tid >> 5;  // V: 32 n-groups x 8 k-groups

  for (int kk0 = 0; kk0 < S_LEN; kk0 += 64) {
    __syncthreads();
    {  // stage K: 64 rows x 128 hw (k_nope | k_rope), swizzled b128 writes
      size_t rowg = (size_t)b * S_LEN + kk0 + kr;
      const u16* srcK = (q4 < 2) ? (kv + rowg * 2560 + h * 64 + q4 * 32)
                                 : (krope + rowg * 64 + (q4 - 2) * 32);
#pragma unroll
      for (int s = 0; s < 4; ++s) {
        short8 v = *(const short8*)(srcK + s * 8);
        *(short8*)&Klds[kaddr(kr, q4 * 4 + s)] = v;
      }
    }
    {  // stage V^T via in-register 8x8 u16 transpose (v_perm)
      const u16* srcV = kv + ((size_t)b * S_LEN + kk0 + vkb * 8) * 2560 + 512 + h * 256 + vn8;
      uint32_t u[8][4];
#pragma unroll
      for (int i = 0; i < 8; ++i) {
        uint4 w = *(const uint4*)(srcV + (size_t)i * 2560);
        u[i][0] = w.x; u[i][1] = w.y; u[i][2] = w.z; u[i][3] = w.w;
      }
#pragma unroll
      for (int j = 0; j < 8; ++j) {
        uint32_t sel = (j & 1) ? 0x07060302u : 0x05040100u;
        int jh = j >> 1;
        uint4 o;
        o.x = __builtin_amdgcn_perm(u[1][jh], u[0][jh], sel);
        o.y = __builtin_amdgcn_perm(u[3][jh], u[2][jh], sel);
        o.z = __builtin_amdgcn_perm(u[5][jh], u[4][jh], sel);
        o.w = __builtin_amdgcn_perm(u[7][jh], u[6][jh], sel);
        *(uint4*)&Vlds[vaddr(vn8 + j, vkb * 8)] = o;
      }
    }
    __syncthreads();

    // S^T = K · Q^T : st[t][r] = S[q=lane15][k = kk0 + t*16 + quad*4 + r] (log2 domain)
    floatx4 st[4];
#pragma unroll
    for (int t = 0; t < 4; ++t) st[t] = (floatx4){0.f, 0.f, 0.f, 0.f};
#pragma unroll
    for (int c = 0; c < 4; ++c) {
      short8 qf = qfrag[c];
#pragma unroll
      for (int t = 0; t < 4; ++t) {
        short8 kf = *(const short8*)&Klds[kaddr(t * 16 + lane15, c * 4 + quad)];
        st[t] = mfma16(kf, qf, st[t]);
      }
    }

    // online softmax (single pass; per-lane scalars; 2-step cross-quad reduce)
    float mloc = st[0][0];
#pragma unroll
    for (int t = 0; t < 4; ++t)
#pragma unroll
      for (int r = 0; r < 4; ++r) mloc = fmaxf(mloc, st[t][r]);
    mloc = fmaxf(mloc, __shfl_xor(mloc, 16));
    mloc = fmaxf(mloc, __shfl_xor(mloc, 32));
    float mnew = fmaxf(m_i, mloc);
    float alpha = exp2f(m_i - mnew);
    float rs = 0.f;
    short8 a01, a23;
#pragma unroll
    for (int t = 0; t < 4; ++t) {
#pragma unroll
      for (int r = 0; r < 4; ++r) {
        float pv = exp2f(st[t][r] - mnew);
        rs += pv;
        u16 pb = f2bf(pv);
        if (t == 0) a01[r] = (short)pb;
        else if (t == 1) a01[4 + r] = (short)pb;
        else if (t == 2) a23[r] = (short)pb;
        else a23[4 + r] = (short)pb;
      }
    }
    rs += __shfl_xor(rs, 16);
    rs += __shfl_xor(rs, 32);
    m_i = mnew;
    l_i = l_i * alpha + rs;

    // broadcast alpha for o_acc rows (o row q' = quad*4+r; alpha lives at lane15=q')
    float al[4];
#pragma unroll
    for (int r = 0; r < 4; ++r) al[r] = __shfl(alpha, quad * 4 + r, 16);

#pragma unroll
    for (int g = 0; g < 16; ++g) {
      floatx4 o = o_acc[g];
      o[0] *= al[0]; o[1] *= al[1]; o[2] *= al[2]; o[3] *= al[3];
      int n = g * 16 + lane15;
      short4v v0 = *(const short4v*)&Vlds[vaddr(n, quad * 4)];
      short4v v1 = *(const short4v*)&Vlds[vaddr(n, 16 + quad * 4)];
      short4v v2 = *(const short4v*)&Vlds[vaddr(n, 32 + quad * 4)];
      short4v v3 = *(const short4v*)&Vlds[vaddr(n, 48 + quad * 4)];
      short8 b01, b23;
#pragma unroll
      for (int i = 0; i < 4; ++i) {
        b01[i] = v0[i]; b01[4 + i] = v1[i];
        b23[i] = v2[i]; b23[4 + i] = v3[i];
      }
      o = mfma16(a01, b01, o);
      o = mfma16(a23, b23, o);
      o_acc[g] = o;
    }
  }

  float rl = 1.0f / l_i;
  float linv[4];
#pragma unroll
  for (int r = 0; r < 4; ++r) linv[r] = __shfl(rl, quad * 4 + r, 16);
#pragma unroll
  for (int g = 0; g < 16; ++g) {
#pragma unroll
    for (int r = 0; r < 4; ++r) {
      int row = qrow0 + quad * 4 + r;
      int col = h * 256 + g * 16 + lane15;
      attn_out[((size_t)b * S_LEN + row) * 2048 + col] = f2bf(o_acc[g][r] * linv[r]);
    }
  }
}

extern "C" void kernel_launch(void* const* d_in, const int* in_sizes, int n_in,
                              void* d_out, int out_size, void* d_ws, size_t ws_size,
                              hipStream_t stream) {
  const float* x = (const float*)d_in[0];
  const int* pos = (const int*)d_in[1];
  const float* wdq = (const float*)d_in[2];
  const float* bdq = (const float*)d_in[3];
  const float* qnw = (const float*)d_in[4];
  const float* wuq = (const float*)d_in[5];
  const float* buq = (const float*)d_in[6];
  const float* wdkv = (const float*)d_in[7];
  const float* bdkv = (const float*)d_in[8];
  const float* kvnw = (const float*)d_in[9];
  const float* wukv = (const float*)d_in[10];
  const float* bukv = (const float*)d_in[11];
  const float* wo = (const float*)d_in[12];
  const float* bo = (const float*)d_in[13];
  float* out = (float*)d_out;

  char* ws = (char*)d_ws;
  size_t off = 0;
  auto alloc = [&](size_t bytes) {
    char* p = ws + off;
    off += (bytes + 255) & ~(size_t)255;
    return p;
  };
  u16* xbf = (u16*)alloc((size_t)R_TOK * 1024 * 2);
  u16* waT = (u16*)alloc((size_t)320 * 1024 * 2);
  float* biasA = (float*)alloc(320 * 4);
  u16* wQT = (u16*)alloc((size_t)1024 * 128 * 2);
  u16* wKVT = (u16*)alloc((size_t)2560 * 128 * 2);
  u16* wOT = (u16*)alloc((size_t)1024 * 2048 * 2);
  float* t0 = (float*)alloc((size_t)R_TOK * 320 * 4);
  u16* cq = (u16*)alloc((size_t)R_TOK * 128 * 2);
  u16* ckv = (u16*)alloc((size_t)R_TOK * 128 * 2);
  u16* krope = (u16*)alloc((size_t)R_TOK * 64 * 2);
  u16* qout = (u16*)alloc((size_t)R_TOK * 1024 * 2);
  u16* qst = (u16*)alloc((size_t)R_TOK * 1024 * 2);
  u16* kvb = (u16*)alloc((size_t)R_TOK * 2560 * 2);
  u16* attnb = (u16*)alloc((size_t)R_TOK * 2048 * 2);
  (void)ws_size; (void)n_in; (void)in_sizes; (void)out_size;

  // converts / weight prep (transposed weights for the BT GEMM)
  k_f2bf<<<(R_TOK * 1024 / 4 + 255) / 256, 256, 0, stream>>>(x, xbf, R_TOK * 1024 / 4);
  k_biascat<<<2, 256, 0, stream>>>(bdq, bdkv, biasA);
  k_tbf_wa<<<dim3(10, 32), dim3(32, 8), 0, stream>>>(wdq, wdkv, waT);
  k_tbf<<<dim3(32, 4), dim3(32, 8), 0, stream>>>(wuq, wQT, 128, 1024);
  k_tbf<<<dim3(80, 4), dim3(32, 8), 0, stream>>>(wukv, wKVT, 128, 2560);
  k_tbf<<<dim3(32, 64), dim3(32, 8), 0, stream>>>(wo, wOT, 2048, 1024);

  // stage A: x @ [w_dq | w_dkv_kr] -> t0 fp32
  k_gemm_bt<0><<<dim3(3, 32), 256, 0, stream>>>(xbf, waT, biasA, t0, R_TOK, 320, 1024);
  k_stagea<<<R_TOK, 128, 0, stream>>>(t0, qnw, kvnw, pos, cq, ckv, krope);
  // stage B: q up-proj, rope+scale+scatter
  k_gemm_bt<1><<<dim3(8, 32), 256, 0, stream>>>(cq, wQT, buq, qout, R_TOK, 1024, 128);
  k_stageb<<<R_TOK, 256, 0, stream>>>(qout, pos, qst);
  // kv up-proj
  k_gemm_bt<1><<<dim3(20, 32), 256, 0, stream>>>(ckv, wKVT, bukv, kvb, R_TOK, 2560, 128);
  // attention
  k_attn<<<dim3(32, 16), 256, 0, stream>>>(qst, kvb, krope, attnb);
  // output projection -> fp32 out
  k_gemm_bt<0><<<dim3(8, 32), 256, 0, stream>>>(attnb, wOT, bo, out, R_TOK, 1024, 2048);
}

// Round 4
// 395.140 us; speedup vs baseline: 1.9178x; 1.9178x over previous
//
#include <hip/hip_runtime.h>
#include <stdint.h>

typedef unsigned short u16;
typedef short short8 __attribute__((ext_vector_type(8)));
typedef float floatx4 __attribute__((ext_vector_type(4)));

#define S_LEN 2048
#define NB 2
#define NH 8
#define R_TOK (NB * S_LEN)  // 4096

// log2(10000)
#define L2_THETA 13.287712379549449f
// attention scale folded into Q, in log2 domain: (1/sqrt(128)) * log2(e)
#define QSCALE (0.08838834764831845f * 1.4426950408889634f)

__device__ inline u16 f2bf(float f) {
  union { float f; uint32_t u; } x; x.f = f;
  uint32_t r = (x.u + 0x7fffu + ((x.u >> 16) & 1u)) >> 16;
  return (u16)r;
}
__device__ inline float bf2f(u16 h) {
  union { uint32_t u; float f; } x; x.u = ((uint32_t)h) << 16;
  return x.f;
}
__device__ inline floatx4 mfma16(short8 a, short8 b, floatx4 c) {
  return __builtin_amdgcn_mfma_f32_16x16x32_bf16(a, b, c, 0, 0, 0);
}

// ---------------- fp32 -> bf16 convert (vectorized) ----------------
__global__ void k_f2bf(const float* __restrict__ in, u16* __restrict__ out, int n4) {
  int i = blockIdx.x * blockDim.x + threadIdx.x;
  if (i < n4) {
    float4 v = ((const float4*)in)[i];
    ushort4 o;
    o.x = f2bf(v.x); o.y = f2bf(v.y); o.z = f2bf(v.z); o.w = f2bf(v.w);
    ((ushort4*)out)[i] = o;
  }
}

// ---------------- tiled fp32 [R][C] -> bf16 transpose [C][R] ----------------
__global__ void k_tbf(const float* __restrict__ in, u16* __restrict__ out, int R, int C) {
  __shared__ u16 t[32][33];
  int c0 = blockIdx.x * 32, r0 = blockIdx.y * 32;
  int tx = threadIdx.x, ty = threadIdx.y;  // 32 x 8
#pragma unroll
  for (int i = 0; i < 4; ++i)
    t[ty + i * 8][tx] = f2bf(in[(size_t)(r0 + ty + i * 8) * C + c0 + tx]);
  __syncthreads();
#pragma unroll
  for (int i = 0; i < 4; ++i)
    out[(size_t)(c0 + ty + i * 8) * R + r0 + tx] = t[tx][ty + i * 8];
}

// concat-transpose: logical in = [1024][320] (wdq cols 0-127, wdkv cols 128-319) -> out [320][1024]
__global__ void k_tbf_wa(const float* __restrict__ wdq, const float* __restrict__ wdkv,
                         u16* __restrict__ out) {
  __shared__ u16 t[32][33];
  int c0 = blockIdx.x * 32, r0 = blockIdx.y * 32;
  int tx = threadIdx.x, ty = threadIdx.y;
#pragma unroll
  for (int i = 0; i < 4; ++i) {
    int r = r0 + ty + i * 8, c = c0 + tx;
    float v = (c < 128) ? wdq[(size_t)r * 128 + c] : wdkv[(size_t)r * 192 + (c - 128)];
    t[ty + i * 8][tx] = f2bf(v);
  }
  __syncthreads();
#pragma unroll
  for (int i = 0; i < 4; ++i)
    out[(size_t)(c0 + ty + i * 8) * 1024 + r0 + tx] = t[tx][ty + i * 8];
}

__global__ void k_biascat(const float* __restrict__ bdq, const float* __restrict__ bdkv,
                          float* __restrict__ biasA) {
  int i = blockIdx.x * 256 + threadIdx.x;
  if (i < 320) biasA[i] = (i < 128) ? bdq[i] : bdkv[i - 128];
}

// ---------------- 128x128-tile GEMM, B given transposed [N][K] ----------------
template <int OUT_BF>
__global__ __launch_bounds__(256) void k_gemm_bt(const u16* __restrict__ A,
                                                 const u16* __restrict__ BT,
                                                 const float* __restrict__ bias,
                                                 void* __restrict__ Cout,
                                                 int M, int N, int K) {
  __shared__ __align__(16) u16 Alds[128 * 32];
  __shared__ __align__(16) u16 Blds[128 * 32];
  const int tid = threadIdx.x;
  const int wave = tid >> 6, lane = tid & 63;
  const int lane15 = lane & 15, quad = lane >> 4;
  const int m0 = blockIdx.y * 128, n0 = blockIdx.x * 128;
  const int mw = (wave & 1) * 64, nw = (wave >> 1) * 64;

  floatx4 acc[4][4];
#pragma unroll
  for (int a = 0; a < 4; ++a)
#pragma unroll
    for (int b = 0; b < 4; ++b) acc[a][b] = (floatx4){0.f, 0.f, 0.f, 0.f};

  const int sr = tid >> 1, sh = (tid & 1) * 16;
  const bool bok = (n0 + sr) < N;

  for (int k0 = 0; k0 < K; k0 += 32) {
    __syncthreads();
    {
      const u16* s = A + (size_t)(m0 + sr) * K + k0 + sh;
      *(short8*)&Alds[sr * 32 + sh] = *(const short8*)s;
      *(short8*)&Alds[sr * 32 + sh + 8] = *(const short8*)(s + 8);
    }
    if (bok) {
      const u16* s = BT + (size_t)(n0 + sr) * K + k0 + sh;
      *(short8*)&Blds[sr * 32 + sh] = *(const short8*)s;
      *(short8*)&Blds[sr * 32 + sh + 8] = *(const short8*)(s + 8);
    }
    __syncthreads();
    short8 af[4], bf[4];
#pragma unroll
    for (int im = 0; im < 4; ++im)
      af[im] = *(const short8*)&Alds[(mw + im * 16 + lane15) * 32 + quad * 8];
#pragma unroll
    for (int in = 0; in < 4; ++in)
      bf[in] = *(const short8*)&Blds[(nw + in * 16 + lane15) * 32 + quad * 8];
#pragma unroll
    for (int im = 0; im < 4; ++im)
#pragma unroll
      for (int in = 0; in < 4; ++in) acc[im][in] = mfma16(af[im], bf[in], acc[im][in]);
  }

#pragma unroll
  for (int im = 0; im < 4; ++im)
#pragma unroll
    for (int in = 0; in < 4; ++in)
#pragma unroll
      for (int r = 0; r < 4; ++r) {
        int row = m0 + mw + im * 16 + quad * 4 + r;
        int col = n0 + nw + in * 16 + lane15;
        if (col < N) {
          float v = acc[im][in][r] + bias[col];
          if (OUT_BF)
            ((u16*)Cout)[(size_t)row * N + col] = f2bf(v);
          else
            ((float*)Cout)[(size_t)row * N + col] = v;
        }
      }
}

// ---------------- stage-A epilogue: rmsnorm(cq), rmsnorm(ckv), rope(k_rope) ----------------
__global__ void k_stagea(const float* __restrict__ t0, const float* __restrict__ qnw,
                         const float* __restrict__ kvnw, const int* __restrict__ pos_ids,
                         u16* __restrict__ cq, u16* __restrict__ ckv,
                         u16* __restrict__ krope) {
  int r = blockIdx.x, tid = threadIdx.x;  // 128 threads
  const float* row = t0 + (size_t)r * 320;
  float a = row[tid];
  float b = row[128 + tid];
  float sa = a * a, sb = b * b;
#pragma unroll
  for (int d = 1; d < 64; d <<= 1) {
    sa += __shfl_xor(sa, d);
    sb += __shfl_xor(sb, d);
  }
  __shared__ float red[4];
  if ((tid & 63) == 0) { red[(tid >> 6) * 2] = sa; red[(tid >> 6) * 2 + 1] = sb; }
  __syncthreads();
  sa = red[0] + red[2];
  sb = red[1] + red[3];
  float ra = rsqrtf(sa * (1.0f / 128.0f) + 1e-8f);
  float rb = rsqrtf(sb * (1.0f / 128.0f) + 1e-8f);
  cq[(size_t)r * 128 + tid] = f2bf(qnw[tid] * a * ra);
  ckv[(size_t)r * 128 + tid] = f2bf(kvnw[tid] * b * rb);
  if (tid < 32) {
    float xe = row[256 + 2 * tid], xo = row[256 + 2 * tid + 1];
    float p = (float)pos_ids[r];
    float freq = exp2f(-(2.0f * tid / 64.0f) * L2_THETA);
    float ang = p * freq;
    float c = cosf(ang), s = sinf(ang);
    krope[(size_t)r * 64 + 2 * tid] = f2bf(xe * c - xo * s);
    krope[(size_t)r * 64 + 2 * tid + 1] = f2bf(xe * s + xo * c);
  }
}

// ---------------- stage-B epilogue: rope(q_rope) + scale + scatter to (B,H,S,128) ----------------
__global__ void k_stageb(const u16* __restrict__ q, const int* __restrict__ pos_ids,
                         u16* __restrict__ qstates) {
  int r = blockIdx.x, tid = threadIdx.x;  // 256 threads
  int b = r >> 11, s = r & (S_LEN - 1);
  float p = (float)pos_ids[r];
#pragma unroll
  for (int i = 0; i < 4; ++i) {
    int idx = tid + i * 256;  // h*128 + d
    int h = idx >> 7, d = idx & 127;
    float val;
    if (d < 96) {
      val = bf2f(q[(size_t)r * 1024 + h * 96 + d]);
    } else {
      int j = d - 96, pr = j >> 1;
      float xe = bf2f(q[(size_t)r * 1024 + 768 + h * 32 + 2 * pr]);
      float xo = bf2f(q[(size_t)r * 1024 + 768 + h * 32 + 2 * pr + 1]);
      float freq = exp2f(-(2.0f * pr / 32.0f) * L2_THETA);
      float ang = p * freq;
      float c = cosf(ang), sn = sinf(ang);
      val = (j & 1) ? (xe * sn + xo * c) : (xe * c - xo * sn);
    }
    qstates[((size_t)(b * NH + h) * S_LEN + s) * 128 + d] = f2bf(val * QSCALE);
  }
}

// ---------------- flash attention, S^T formulation ----------------
// Block = (b,h) x 64 q-rows, 4 waves (16 q-rows each). K-chunk = 64.
// Grid: blockIdx.x = pair (16) so all 32 q-blocks of a pair share one XCD (lin%8 = pair%8)
// -> per-XCD L2 working set = 2 pairs x 1.5MB = 3MB < 4MB.
// S^T = K * Q^T: lane holds S[q=lane15][k=t*16+quad*4+r] -> P directly in A-operand order.
// V^T stored in LDS in PERMUTED-K order so each PV b-fragment is one ds_read_b128:
//   pos(k): c=k>>5, q=((k&31)>>2)&3, t=(k>>4)&1, r=k&3 -> unit=(c*4+q), idx=t*4+r
//   unit swizzled: unit' = (unit ^ n ^ (n>>3)) & 7. Read b01: unit=quad, b23: unit=4+quad.
__device__ inline int kaddr(int row, int u) {
  return row * 128 + (((u & 8) | ((u ^ row) & 7)) << 3);
}
__device__ inline int vswz(int n) { return (n ^ (n >> 3)) & 7; }

__global__ __launch_bounds__(256) void k_attn(const u16* __restrict__ qstates,
                                              const u16* __restrict__ kv,
                                              const u16* __restrict__ krope,
                                              u16* __restrict__ attn_out) {
  const int pair = blockIdx.x;  // 0..15
  const int qblk = blockIdx.y;  // 0..31
  const int b = pair >> 3, h = pair & 7;
  const int tid = threadIdx.x;
  const int wave = tid >> 6, lane = tid & 63;
  const int lane15 = lane & 15, quad = lane >> 4;

  __shared__ __align__(16) u16 Klds[64 * 128];  // 16 KB
  __shared__ __align__(16) u16 Vlds[256 * 64];  // 32 KB

  const int qrow0 = qblk * 64 + wave * 16;
  short8 qfrag[4];
  {
    const u16* qb = qstates + ((size_t)(b * NH + h) * S_LEN + qrow0 + lane15) * 128 + quad * 8;
#pragma unroll
    for (int c = 0; c < 4; ++c) qfrag[c] = *(const short8*)(qb + c * 32);
  }

  floatx4 o_acc[16];
#pragma unroll
  for (int g = 0; g < 16; ++g) o_acc[g] = (floatx4){0.f, 0.f, 0.f, 0.f};
  float m_i = -1e30f, l_i = 0.f;  // per-lane; q-row = lane15 (replicated across quads)

  const int kr = tid >> 2, q4 = tid & 3;           // K: 64 rows x 4 quarters
  const int vn8 = (tid & 31) * 8, vkb = tid >> 5;  // V: 32 n-groups x 8 k-groups
  // V staging write targets (constant across iterations)
  const int vc = vkb >> 2, vt = (vkb >> 1) & 1;
  const int vqlo = (2 * vkb) & 3, vqhi = (2 * vkb + 1) & 3;

  for (int kk0 = 0; kk0 < S_LEN; kk0 += 64) {
    __syncthreads();
    {  // stage K: 64 rows x 128 hw (k_nope | k_rope), swizzled b128 writes
      size_t rowg = (size_t)b * S_LEN + kk0 + kr;
      const u16* srcK = (q4 < 2) ? (kv + rowg * 2560 + h * 64 + q4 * 32)
                                 : (krope + rowg * 64 + (q4 - 2) * 32);
#pragma unroll
      for (int s = 0; s < 4; ++s) {
        short8 v = *(const short8*)(srcK + s * 8);
        *(short8*)&Klds[kaddr(kr, q4 * 4 + s)] = v;
      }
    }
    {  // stage V^T via in-register 8x8 u16 transpose, store in permuted-k order
      const u16* srcV = kv + ((size_t)b * S_LEN + kk0 + vkb * 8) * 2560 + 512 + h * 256 + vn8;
      uint32_t u[8][4];
#pragma unroll
      for (int i = 0; i < 8; ++i) {
        uint4 w = *(const uint4*)(srcV + (size_t)i * 2560);
        u[i][0] = w.x; u[i][1] = w.y; u[i][2] = w.z; u[i][3] = w.w;
      }
#pragma unroll
      for (int j = 0; j < 8; ++j) {
        uint32_t sel = (j & 1) ? 0x07060302u : 0x05040100u;
        int jh = j >> 1;
        int n = vn8 + j;
        int sw = vswz(n);
        uint2 lo, hi;
        lo.x = __builtin_amdgcn_perm(u[1][jh], u[0][jh], sel);
        lo.y = __builtin_amdgcn_perm(u[3][jh], u[2][jh], sel);
        hi.x = __builtin_amdgcn_perm(u[5][jh], u[4][jh], sel);
        hi.y = __builtin_amdgcn_perm(u[7][jh], u[6][jh], sel);
        *(uint2*)&Vlds[n * 64 + (((vc * 4 + vqlo) ^ sw) & 7) * 8 + vt * 4] = lo;
        *(uint2*)&Vlds[n * 64 + (((vc * 4 + vqhi) ^ sw) & 7) * 8 + vt * 4] = hi;
      }
    }
    __syncthreads();

    // S^T = K * Q^T : st[t][r] = S[q=lane15][k = t*16 + quad*4 + r] (log2 domain)
    floatx4 st[4];
#pragma unroll
    for (int t = 0; t < 4; ++t) st[t] = (floatx4){0.f, 0.f, 0.f, 0.f};
#pragma unroll
    for (int c = 0; c < 4; ++c) {
      short8 qf = qfrag[c];
#pragma unroll
      for (int t = 0; t < 4; ++t) {
        short8 kf = *(const short8*)&Klds[kaddr(t * 16 + lane15, c * 4 + quad)];
        st[t] = mfma16(kf, qf, st[t]);
      }
    }

    // online softmax (single pass; per-lane scalars; 2-step cross-quad reduce)
    float mloc = st[0][0];
#pragma unroll
    for (int t = 0; t < 4; ++t)
#pragma unroll
      for (int r = 0; r < 4; ++r) mloc = fmaxf(mloc, st[t][r]);
    mloc = fmaxf(mloc, __shfl_xor(mloc, 16));
    mloc = fmaxf(mloc, __shfl_xor(mloc, 32));
    float mnew = fmaxf(m_i, mloc);
    float alpha = exp2f(m_i - mnew);
    float rs = 0.f;
    short8 a01, a23;
#pragma unroll
    for (int t = 0; t < 4; ++t) {
#pragma unroll
      for (int r = 0; r < 4; ++r) {
        float pv = exp2f(st[t][r] - mnew);
        rs += pv;
        u16 pb = f2bf(pv);
        if (t == 0) a01[r] = (short)pb;
        else if (t == 1) a01[4 + r] = (short)pb;
        else if (t == 2) a23[r] = (short)pb;
        else a23[4 + r] = (short)pb;
      }
    }
    rs += __shfl_xor(rs, 16);
    rs += __shfl_xor(rs, 32);
    m_i = mnew;
    l_i = l_i * alpha + rs;

    // broadcast alpha for o_acc rows (o row q' = quad*4+r; alpha lives at lane15=q')
    float al[4];
#pragma unroll
    for (int r = 0; r < 4; ++r) al[r] = __shfl(alpha, quad * 4 + r, 16);

#pragma unroll
    for (int g = 0; g < 16; ++g) {
      floatx4 o = o_acc[g];
      o[0] *= al[0]; o[1] *= al[1]; o[2] *= al[2]; o[3] *= al[3];
      int n = g * 16 + lane15;
      int sw = vswz(n);
      short8 b01 = *(const short8*)&Vlds[n * 64 + ((quad ^ sw) & 7) * 8];
      short8 b23 = *(const short8*)&Vlds[n * 64 + (((4 + quad) ^ sw) & 7) * 8];
      o = mfma16(a01, b01, o);
      o = mfma16(a23, b23, o);
      o_acc[g] = o;
    }
  }

  float rl = 1.0f / l_i;
  float linv[4];
#pragma unroll
  for (int r = 0; r < 4; ++r) linv[r] = __shfl(rl, quad * 4 + r, 16);
#pragma unroll
  for (int g = 0; g < 16; ++g) {
#pragma unroll
    for (int r = 0; r < 4; ++r) {
      int row = qrow0 + quad * 4 + r;
      int col = h * 256 + g * 16 + lane15;
      attn_out[((size_t)b * S_LEN + row) * 2048 + col] = f2bf(o_acc[g][r] * linv[r]);
    }
  }
}

extern "C" void kernel_launch(void* const* d_in, const int* in_sizes, int n_in,
                              void* d_out, int out_size, void* d_ws, size_t ws_size,
                              hipStream_t stream) {
  const float* x = (const float*)d_in[0];
  const int* pos = (const int*)d_in[1];
  const float* wdq = (const float*)d_in[2];
  const float* bdq = (const float*)d_in[3];
  const float* qnw = (const float*)d_in[4];
  const float* wuq = (const float*)d_in[5];
  const float* buq = (const float*)d_in[6];
  const float* wdkv = (const float*)d_in[7];
  const float* bdkv = (const float*)d_in[8];
  const float* kvnw = (const float*)d_in[9];
  const float* wukv = (const float*)d_in[10];
  const float* bukv = (const float*)d_in[11];
  const float* wo = (const float*)d_in[12];
  const float* bo = (const float*)d_in[13];
  float* out = (float*)d_out;

  char* ws = (char*)d_ws;
  size_t off = 0;
  auto alloc = [&](size_t bytes) {
    char* p = ws + off;
    off += (bytes + 255) & ~(size_t)255;
    return p;
  };
  u16* xbf = (u16*)alloc((size_t)R_TOK * 1024 * 2);
  u16* waT = (u16*)alloc((size_t)320 * 1024 * 2);
  float* biasA = (float*)alloc(320 * 4);
  u16* wQT = (u16*)alloc((size_t)1024 * 128 * 2);
  u16* wKVT = (u16*)alloc((size_t)2560 * 128 * 2);
  u16* wOT = (u16*)alloc((size_t)1024 * 2048 * 2);
  float* t0 = (float*)alloc((size_t)R_TOK * 320 * 4);
  u16* cq = (u16*)alloc((size_t)R_TOK * 128 * 2);
  u16* ckv = (u16*)alloc((size_t)R_TOK * 128 * 2);
  u16* krope = (u16*)alloc((size_t)R_TOK * 64 * 2);
  u16* qout = (u16*)alloc((size_t)R_TOK * 1024 * 2);
  u16* qst = (u16*)alloc((size_t)R_TOK * 1024 * 2);
  u16* kvb = (u16*)alloc((size_t)R_TOK * 2560 * 2);
  u16* attnb = (u16*)alloc((size_t)R_TOK * 2048 * 2);
  (void)ws_size; (void)n_in; (void)in_sizes; (void)out_size;

  // converts / weight prep (transposed weights for the BT GEMM)
  k_f2bf<<<(R_TOK * 1024 / 4 + 255) / 256, 256, 0, stream>>>(x, xbf, R_TOK * 1024 / 4);
  k_biascat<<<2, 256, 0, stream>>>(bdq, bdkv, biasA);
  k_tbf_wa<<<dim3(10, 32), dim3(32, 8), 0, stream>>>(wdq, wdkv, waT);
  k_tbf<<<dim3(32, 4), dim3(32, 8), 0, stream>>>(wuq, wQT, 128, 1024);
  k_tbf<<<dim3(80, 4), dim3(32, 8), 0, stream>>>(wukv, wKVT, 128, 2560);
  k_tbf<<<dim3(32, 64), dim3(32, 8), 0, stream>>>(wo, wOT, 2048, 1024);

  // stage A: x @ [w_dq | w_dkv_kr] -> t0 fp32
  k_gemm_bt<0><<<dim3(3, 32), 256, 0, stream>>>(xbf, waT, biasA, t0, R_TOK, 320, 1024);
  k_stagea<<<R_TOK, 128, 0, stream>>>(t0, qnw, kvnw, pos, cq, ckv, krope);
  // stage B: q up-proj, rope+scale+scatter
  k_gemm_bt<1><<<dim3(8, 32), 256, 0, stream>>>(cq, wQT, buq, qout, R_TOK, 1024, 128);
  k_stageb<<<R_TOK, 256, 0, stream>>>(qout, pos, qst);
  // kv up-proj
  k_gemm_bt<1><<<dim3(20, 32), 256, 0, stream>>>(ckv, wKVT, bukv, kvb, R_TOK, 2560, 128);
  // attention (pair-major grid: all q-blocks of a (b,h) pair on one XCD)
  k_attn<<<dim3(16, 32), 256, 0, stream>>>(qst, kvb, krope, attnb);
  // output projection -> fp32 out
  k_gemm_bt<0><<<dim3(8, 32), 256, 0, stream>>>(attnb, wOT, bo, out, R_TOK, 1024, 2048);
}

// Round 5
// 311.009 us; speedup vs baseline: 2.4366x; 1.2705x over previous
//
#include <hip/hip_runtime.h>
#include <hip/hip_bf16.h>
#include <stdint.h>

typedef unsigned short u16;
typedef short short8 __attribute__((ext_vector_type(8)));
typedef float floatx4 __attribute__((ext_vector_type(4)));

#define S_LEN 2048
#define NB 2
#define NH 8
#define R_TOK (NB * S_LEN)  // 4096

// log2(10000)
#define L2_THETA 13.287712379549449f
// attention scale folded into Q, in log2 domain: (1/sqrt(128)) * log2(e)
#define QSCALE (0.08838834764831845f * 1.4426950408889634f)

__device__ inline u16 f2bf(float f) {
  union { float f; uint32_t u; } x; x.f = f;
  uint32_t r = (x.u + 0x7fffu + ((x.u >> 16) & 1u)) >> 16;
  return (u16)r;
}
__device__ inline float bf2f(u16 h) {
  union { uint32_t u; float f; } x; x.u = ((uint32_t)h) << 16;
  return x.f;
}
__device__ inline floatx4 mfma16(short8 a, short8 b, floatx4 c) {
  return __builtin_amdgcn_mfma_f32_16x16x32_bf16(a, b, c, 0, 0, 0);
}
// packed fp32x2 -> bf16x2 (RNE)
__device__ inline uint32_t pkbf(float a, float b) {
  union { __hip_bfloat162 h; uint32_t u; } c;
  c.h = __float22bfloat162_rn(make_float2(a, b));
  return c.u;
}
// async global(16B) -> LDS, wave-uniform-base + lane*16 dest (CK-style AS casts)
__device__ __forceinline__ void cp16(const void* g, const void* l) {
  __builtin_amdgcn_global_load_lds(
      (const __attribute__((address_space(1))) uint32_t*)(uintptr_t)g,
      (__attribute__((address_space(3))) uint32_t*)(uintptr_t)l, 16, 0, 0);
}

// ---------------- fused prep: x->bf16, weight transposes, bias concat ----------------
__global__ __launch_bounds__(256) void k_prep(
    const float* __restrict__ x, u16* __restrict__ xbf,
    const float* __restrict__ wdq, const float* __restrict__ wdkv, u16* __restrict__ waT,
    const float* __restrict__ wuq, u16* __restrict__ wQT,
    const float* __restrict__ wukv, u16* __restrict__ wKVT,
    const float* __restrict__ wo, u16* __restrict__ wOT,
    const float* __restrict__ bdq, const float* __restrict__ bdkv,
    float* __restrict__ biasA) {
  __shared__ u16 tile[32][33];
  const int s = blockIdx.x, tid = threadIdx.x;
  const int tx = tid & 31, ty = tid >> 5;
  if (s < 4096) {  // x fp32 -> bf16, 4 elems/thread
    int i = s * 256 + tid;
    float4 v = ((const float4*)x)[i];
    ushort4 o;
    o.x = f2bf(v.x); o.y = f2bf(v.y); o.z = f2bf(v.z); o.w = f2bf(v.w);
    ((ushort4*)xbf)[i] = o;
  } else if (s < 4416) {  // waT: logical [1024][320] -> [320][1024]
    int t = s - 4096, bx = t % 10, by = t / 10;
    int c0 = bx * 32, r0 = by * 32;
#pragma unroll
    for (int i = 0; i < 4; ++i) {
      int r = r0 + ty + i * 8, c = c0 + tx;
      float v = (c < 128) ? wdq[(size_t)r * 128 + c] : wdkv[(size_t)r * 192 + (c - 128)];
      tile[ty + i * 8][tx] = f2bf(v);
    }
    __syncthreads();
#pragma unroll
    for (int i = 0; i < 4; ++i)
      waT[(size_t)(c0 + ty + i * 8) * 1024 + r0 + tx] = tile[tx][ty + i * 8];
  } else {
    const float* in; u16* out; int R, C, bx, by;
    if (s < 4544) { int t = s - 4416; in = wuq; out = wQT; R = 128; C = 1024; bx = t & 31; by = t >> 5; }
    else if (s < 4864) { int t = s - 4544; in = wukv; out = wKVT; R = 128; C = 2560; bx = t % 80; by = t / 80; }
    else if (s < 6912) { int t = s - 4864; in = wo; out = wOT; R = 2048; C = 1024; bx = t & 31; by = t >> 5; }
    else {
      if (tid < 320) biasA[tid] = (tid < 128) ? bdq[tid] : bdkv[tid - 128];
      return;
    }
    int c0 = bx * 32, r0 = by * 32;
#pragma unroll
    for (int i = 0; i < 4; ++i)
      tile[ty + i * 8][tx] = f2bf(in[(size_t)(r0 + ty + i * 8) * C + c0 + tx]);
    __syncthreads();
#pragma unroll
    for (int i = 0; i < 4; ++i)
      out[(size_t)(c0 + ty + i * 8) * R + r0 + tx] = tile[tx][ty + i * 8];
  }
}

// ---------------- 128x128-tile GEMM, B transposed [N][K], async LDS staging ----------------
// N not mult of 128 handled by PADDED BT allocation (reads garbage, epilogue guards stores).
template <int OUT_BF>
__global__ __launch_bounds__(256) void k_gemm_bt(const u16* __restrict__ A,
                                                 const u16* __restrict__ BT,
                                                 const float* __restrict__ bias,
                                                 void* __restrict__ Cout,
                                                 int M, int N, int K) {
  __shared__ __align__(16) u16 Alds[128 * 32];
  __shared__ __align__(16) u16 Blds[128 * 32];
  const int tid = threadIdx.x;
  const int wave = tid >> 6, lane = tid & 63;
  const int lane15 = lane & 15, quad = lane >> 4;
  const int m0 = blockIdx.y * 128, n0 = blockIdx.x * 128;
  const int mw = (wave & 1) * 64, nw = (wave >> 1) * 64;

  floatx4 acc[4][4];
#pragma unroll
  for (int a = 0; a < 4; ++a)
#pragma unroll
    for (int b = 0; b < 4; ++b) acc[a][b] = (floatx4){0.f, 0.f, 0.f, 0.f};

  const int srow = wave * 32 + (lane >> 2);   // staging row (this wave covers rows +0 and +16)
  const int scol = (lane & 3) * 8;            // u16 col within 32-wide k-slab

  for (int k0 = 0; k0 < K; k0 += 32) {
    __syncthreads();
    {
      const u16* ga = A + (size_t)(m0 + srow) * K + k0 + scol;
      cp16(ga, Alds + srow * 32 + scol);
      cp16(ga + (size_t)16 * K, Alds + (srow + 16) * 32 + scol);
      const u16* gb = BT + (size_t)(n0 + srow) * K + k0 + scol;
      cp16(gb, Blds + srow * 32 + scol);
      cp16(gb + (size_t)16 * K, Blds + (srow + 16) * 32 + scol);
    }
    __syncthreads();
    short8 af[4], bf[4];
#pragma unroll
    for (int im = 0; im < 4; ++im)
      af[im] = *(const short8*)&Alds[(mw + im * 16 + lane15) * 32 + quad * 8];
#pragma unroll
    for (int in = 0; in < 4; ++in)
      bf[in] = *(const short8*)&Blds[(nw + in * 16 + lane15) * 32 + quad * 8];
#pragma unroll
    for (int im = 0; im < 4; ++im)
#pragma unroll
      for (int in = 0; in < 4; ++in) acc[im][in] = mfma16(af[im], bf[in], acc[im][in]);
  }

#pragma unroll
  for (int im = 0; im < 4; ++im)
#pragma unroll
    for (int in = 0; in < 4; ++in)
#pragma unroll
      for (int r = 0; r < 4; ++r) {
        int row = m0 + mw + im * 16 + quad * 4 + r;
        int col = n0 + nw + in * 16 + lane15;
        if (col < N) {
          float v = acc[im][in][r] + bias[col];
          if (OUT_BF)
            ((u16*)Cout)[(size_t)row * N + col] = f2bf(v);
          else
            ((float*)Cout)[(size_t)row * N + col] = v;
        }
      }
}

// ---------------- stage-A epilogue: rmsnorm(cq), rmsnorm(ckv), rope(k_rope) ----------------
__global__ void k_stagea(const float* __restrict__ t0, const float* __restrict__ qnw,
                         const float* __restrict__ kvnw, const int* __restrict__ pos_ids,
                         u16* __restrict__ cq, u16* __restrict__ ckv,
                         u16* __restrict__ krope) {
  int r = blockIdx.x, tid = threadIdx.x;  // 128 threads
  const float* row = t0 + (size_t)r * 320;
  float a = row[tid];
  float b = row[128 + tid];
  float sa = a * a, sb = b * b;
#pragma unroll
  for (int d = 1; d < 64; d <<= 1) {
    sa += __shfl_xor(sa, d);
    sb += __shfl_xor(sb, d);
  }
  __shared__ float red[4];
  if ((tid & 63) == 0) { red[(tid >> 6) * 2] = sa; red[(tid >> 6) * 2 + 1] = sb; }
  __syncthreads();
  sa = red[0] + red[2];
  sb = red[1] + red[3];
  float ra = rsqrtf(sa * (1.0f / 128.0f) + 1e-8f);
  float rb = rsqrtf(sb * (1.0f / 128.0f) + 1e-8f);
  cq[(size_t)r * 128 + tid] = f2bf(qnw[tid] * a * ra);
  ckv[(size_t)r * 128 + tid] = f2bf(kvnw[tid] * b * rb);
  if (tid < 32) {
    float xe = row[256 + 2 * tid], xo = row[256 + 2 * tid + 1];
    float p = (float)pos_ids[r];
    float freq = exp2f(-(2.0f * tid / 64.0f) * L2_THETA);
    float ang = p * freq;
    float c = cosf(ang), s = sinf(ang);
    krope[(size_t)r * 64 + 2 * tid] = f2bf(xe * c - xo * s);
    krope[(size_t)r * 64 + 2 * tid + 1] = f2bf(xe * s + xo * c);
  }
}

// ---------------- stage-B epilogue: rope(q_rope) + scale + scatter to (B,H,S,128) ----------------
__global__ void k_stageb(const u16* __restrict__ q, const int* __restrict__ pos_ids,
                         u16* __restrict__ qstates) {
  int r = blockIdx.x, tid = threadIdx.x;  // 256 threads
  int b = r >> 11, s = r & (S_LEN - 1);
  float p = (float)pos_ids[r];
#pragma unroll
  for (int i = 0; i < 4; ++i) {
    int idx = tid + i * 256;  // h*128 + d
    int h = idx >> 7, d = idx & 127;
    float val;
    if (d < 96) {
      val = bf2f(q[(size_t)r * 1024 + h * 96 + d]);
    } else {
      int j = d - 96, pr = j >> 1;
      float xe = bf2f(q[(size_t)r * 1024 + 768 + h * 32 + 2 * pr]);
      float xo = bf2f(q[(size_t)r * 1024 + 768 + h * 32 + 2 * pr + 1]);
      float freq = exp2f(-(2.0f * pr / 32.0f) * L2_THETA);
      float ang = p * freq;
      float c = cosf(ang), sn = sinf(ang);
      val = (j & 1) ? (xe * sn + xo * c) : (xe * c - xo * sn);
    }
    qstates[((size_t)(b * NH + h) * S_LEN + s) * 128 + d] = f2bf(val * QSCALE);
  }
}

// ---------------- flash attention, S^T formulation, software-pipelined ----------------
// Block = (b,h) x 64 q-rows, 4 waves (16 q-rows each). K-chunk = 64.
// K: async global_load_lds (double-buffered 2x16KB), UNIT-MAJOR layout:
//   u16 offset = ((g*16 + u)*16 + r)*8   (g=row>>4, r=row&15, u = 16B-unit = dim/8)
//   -> wave-op dest is base + lane*16 with lane=(u_local*16+r); reads conflict-free, no swizzle.
// V: register prefetch (next chunk) + in-register 8x8 transpose -> b128 swizzled writes.
//   unit u=c*4+q holds k={32c+4q+r} u {32c+16+4q+r}, idx=t*4+r (matches P a-frag perm order).
// Loads issue AFTER barrier B, drain at NEXT iter's barrier A (compute in between).
__device__ inline int vswz(int n) { return (n ^ (n >> 3)) & 7; }

__global__ __launch_bounds__(256) void k_attn(const u16* __restrict__ qstates,
                                              const u16* __restrict__ kv,
                                              const u16* __restrict__ krope,
                                              u16* __restrict__ attn_out) {
  const int pair = blockIdx.x;  // 0..15 (pair-major: all q-blocks of a pair on one XCD)
  const int qblk = blockIdx.y;  // 0..31
  const int b = pair >> 3, h = pair & 7;
  const int tid = threadIdx.x;
  const int wave = tid >> 6, lane = tid & 63;
  const int lane15 = lane & 15, quad = lane >> 4;

  __shared__ __align__(16) u16 Klds[2][64 * 128];  // 2 x 16 KB, unit-major
  __shared__ __align__(16) u16 Vlds[256 * 64];     // 32 KB

  const int qrow0 = qblk * 64 + wave * 16;
  short8 qfrag[4];
  {
    const u16* qb = qstates + ((size_t)(b * NH + h) * S_LEN + qrow0 + lane15) * 128 + quad * 8;
#pragma unroll
    for (int c = 0; c < 4; ++c) qfrag[c] = *(const short8*)(qb + c * 32);
  }

  floatx4 o_acc[16];
#pragma unroll
  for (int g = 0; g < 16; ++g) o_acc[g] = (floatx4){0.f, 0.f, 0.f, 0.f};
  float m_i = -1e30f, l_i = 0.f;  // per-lane; q-row = lane15 (replicated across quads)

  // K async staging: this wave issues rowgroup g=wave, 4 ops (u-quads j=0..3)
  const int krow = lane15;           // r within rowgroup
  const int kul = lane >> 4;         // u_local within op
  // V staging: vkb = (c,q); thread loads rows {c*32+q*4+r, +16} and all t, cols vn8..vn8+7
  const int vn8 = (tid & 31) * 8, vkb = tid >> 5;
  const int vrow0 = (vkb >> 2) * 32 + (vkb & 3) * 4;

  uint32_t vr[8][4];  // V prefetch regs (8 rows x 16B)

  auto issueK = [&](int kk0, u16* kbuf) {
    size_t rowg = (size_t)b * S_LEN + kk0 + wave * 16 + krow;
    const u16* gk = kv + rowg * 2560 + h * 64;
    const u16* gr = krope + rowg * 64;
#pragma unroll
    for (int j = 0; j < 4; ++j) {
      int u = 4 * j + kul;
      const u16* g = (j < 2) ? (gk + u * 8) : (gr + (u - 8) * 8);
      cp16(g, kbuf + ((wave * 16 + 4 * j) * 16 + lane) * 8);
    }
  };
  auto loadV = [&](int kk0) {
    const u16* srcV = kv + ((size_t)b * S_LEN + kk0 + vrow0) * 2560 + 512 + h * 256 + vn8;
#pragma unroll
    for (int i = 0; i < 8; ++i) {
      int ro = (i & 3) + ((i >> 2) * 16);
      uint4 w = *(const uint4*)(srcV + (size_t)ro * 2560);
      vr[i][0] = w.x; vr[i][1] = w.y; vr[i][2] = w.z; vr[i][3] = w.w;
    }
  };

  // preamble: chunk 0 in flight
  issueK(0, Klds[0]);
  loadV(0);
  int cur = 0;

  for (int ch = 0; ch < S_LEN / 64; ++ch) {
    __syncthreads();  // A: drains K[cur] async + V regs; prev Vlds reads done
    {  // write V chunk ch: 8x8 u16 transpose -> b128 swizzled stores
#pragma unroll
      for (int j = 0; j < 8; ++j) {
        uint32_t sel = (j & 1) ? 0x07060302u : 0x05040100u;
        int jh = j >> 1;
        uint4 o;
        o.x = __builtin_amdgcn_perm(vr[1][jh], vr[0][jh], sel);
        o.y = __builtin_amdgcn_perm(vr[3][jh], vr[2][jh], sel);
        o.z = __builtin_amdgcn_perm(vr[5][jh], vr[4][jh], sel);
        o.w = __builtin_amdgcn_perm(vr[7][jh], vr[6][jh], sel);
        int n = vn8 + j;
        *(uint4*)&Vlds[n * 64 + ((vkb ^ vswz(n)) & 7) * 8] = o;
      }
    }
    __syncthreads();  // B: Vlds + Klds[cur] visible; nothing outstanding to drain
    if (ch + 1 < S_LEN / 64) {  // prefetch chunk ch+1 (drains at next barrier A)
      issueK((ch + 1) * 64, Klds[cur ^ 1]);
      loadV((ch + 1) * 64);
    }

    // S^T = K * Q^T : st[t][r] = S[q=lane15][k = t*16 + quad*4 + r] (log2 domain)
    const u16* kbuf = Klds[cur];
    floatx4 st[4];
#pragma unroll
    for (int t = 0; t < 4; ++t) st[t] = (floatx4){0.f, 0.f, 0.f, 0.f};
#pragma unroll
    for (int c = 0; c < 4; ++c) {
      short8 qf = qfrag[c];
#pragma unroll
      for (int t = 0; t < 4; ++t) {
        short8 kf = *(const short8*)&kbuf[((t * 16 + c * 4 + quad) * 16 + lane15) * 8];
        st[t] = mfma16(kf, qf, st[t]);
      }
    }

    // online softmax (per-lane scalars, 2-shfl reduce, packed bf16 cvt)
    float mloc = st[0][0];
#pragma unroll
    for (int t = 0; t < 4; ++t)
#pragma unroll
      for (int r = 0; r < 4; ++r) mloc = fmaxf(mloc, st[t][r]);
    mloc = fmaxf(mloc, __shfl_xor(mloc, 16));
    mloc = fmaxf(mloc, __shfl_xor(mloc, 32));
    float mnew = fmaxf(m_i, mloc);
    float rs = 0.f;
    union { short8 s; uint4 u; } a01, a23;
    {
      float p0, p1, p2, p3;
      p0 = exp2f(st[0][0] - mnew); p1 = exp2f(st[0][1] - mnew);
      p2 = exp2f(st[0][2] - mnew); p3 = exp2f(st[0][3] - mnew);
      rs += (p0 + p1) + (p2 + p3);
      a01.u.x = pkbf(p0, p1); a01.u.y = pkbf(p2, p3);
      p0 = exp2f(st[1][0] - mnew); p1 = exp2f(st[1][1] - mnew);
      p2 = exp2f(st[1][2] - mnew); p3 = exp2f(st[1][3] - mnew);
      rs += (p0 + p1) + (p2 + p3);
      a01.u.z = pkbf(p0, p1); a01.u.w = pkbf(p2, p3);
      p0 = exp2f(st[2][0] - mnew); p1 = exp2f(st[2][1] - mnew);
      p2 = exp2f(st[2][2] - mnew); p3 = exp2f(st[2][3] - mnew);
      rs += (p0 + p1) + (p2 + p3);
      a23.u.x = pkbf(p0, p1); a23.u.y = pkbf(p2, p3);
      p0 = exp2f(st[3][0] - mnew); p1 = exp2f(st[3][1] - mnew);
      p2 = exp2f(st[3][2] - mnew); p3 = exp2f(st[3][3] - mnew);
      rs += (p0 + p1) + (p2 + p3);
      a23.u.z = pkbf(p0, p1); a23.u.w = pkbf(p2, p3);
    }
    rs += __shfl_xor(rs, 16);
    rs += __shfl_xor(rs, 32);

    if (__any(mloc > m_i)) {  // running max changed for some q-row: rescale
      float alpha = exp2f(m_i - mnew);
      l_i = l_i * alpha + rs;
      m_i = mnew;
      float al[4];
#pragma unroll
      for (int r = 0; r < 4; ++r) al[r] = __shfl(alpha, quad * 4 + r, 16);
#pragma unroll
      for (int g = 0; g < 16; ++g) {
        o_acc[g][0] *= al[0]; o_acc[g][1] *= al[1];
        o_acc[g][2] *= al[2]; o_acc[g][3] *= al[3];
      }
    } else {
      l_i += rs;
    }

    // PV: b-frags are single b128 reads (permuted-k V layout)
#pragma unroll
    for (int g = 0; g < 16; ++g) {
      int n = g * 16 + lane15;
      int sw = vswz(n);
      short8 b01 = *(const short8*)&Vlds[n * 64 + ((quad ^ sw) & 7) * 8];
      short8 b23 = *(const short8*)&Vlds[n * 64 + (((quad | 4) ^ sw) & 7) * 8];
      floatx4 o = o_acc[g];
      o = mfma16(a01.s, b01, o);
      o = mfma16(a23.s, b23, o);
      o_acc[g] = o;
    }
    cur ^= 1;
  }

  float rl = 1.0f / l_i;
  float linv[4];
#pragma unroll
  for (int r = 0; r < 4; ++r) linv[r] = __shfl(rl, quad * 4 + r, 16);
#pragma unroll
  for (int g = 0; g < 16; ++g) {
#pragma unroll
    for (int r = 0; r < 4; ++r) {
      int row = qrow0 + quad * 4 + r;
      int col = h * 256 + g * 16 + lane15;
      attn_out[((size_t)b * S_LEN + row) * 2048 + col] = f2bf(o_acc[g][r] * linv[r]);
    }
  }
}

extern "C" void kernel_launch(void* const* d_in, const int* in_sizes, int n_in,
                              void* d_out, int out_size, void* d_ws, size_t ws_size,
                              hipStream_t stream) {
  const float* x = (const float*)d_in[0];
  const int* pos = (const int*)d_in[1];
  const float* wdq = (const float*)d_in[2];
  const float* bdq = (const float*)d_in[3];
  const float* qnw = (const float*)d_in[4];
  const float* wuq = (const float*)d_in[5];
  const float* buq = (const float*)d_in[6];
  const float* wdkv = (const float*)d_in[7];
  const float* bdkv = (const float*)d_in[8];
  const float* kvnw = (const float*)d_in[9];
  const float* wukv = (const float*)d_in[10];
  const float* bukv = (const float*)d_in[11];
  const float* wo = (const float*)d_in[12];
  const float* bo = (const float*)d_in[13];
  float* out = (float*)d_out;

  char* ws = (char*)d_ws;
  size_t off = 0;
  auto alloc = [&](size_t bytes) {
    char* p = ws + off;
    off += (bytes + 255) & ~(size_t)255;
    return p;
  };
  u16* xbf = (u16*)alloc((size_t)R_TOK * 1024 * 2);
  u16* waT = (u16*)alloc((size_t)384 * 1024 * 2);  // padded 320->384 rows (async staging OOB safety)
  float* biasA = (float*)alloc(320 * 4);
  u16* wQT = (u16*)alloc((size_t)1024 * 128 * 2);
  u16* wKVT = (u16*)alloc((size_t)2560 * 128 * 2);
  u16* wOT = (u16*)alloc((size_t)1024 * 2048 * 2);
  float* t0 = (float*)alloc((size_t)R_TOK * 320 * 4);
  u16* cq = (u16*)alloc((size_t)R_TOK * 128 * 2);
  u16* ckv = (u16*)alloc((size_t)R_TOK * 128 * 2);
  u16* krope = (u16*)alloc((size_t)R_TOK * 64 * 2);
  u16* qout = (u16*)alloc((size_t)R_TOK * 1024 * 2);
  u16* qst = (u16*)alloc((size_t)R_TOK * 1024 * 2);
  u16* kvb = (u16*)alloc((size_t)R_TOK * 2560 * 2);
  u16* attnb = (u16*)alloc((size_t)R_TOK * 2048 * 2);
  (void)ws_size; (void)n_in; (void)in_sizes; (void)out_size;

  // fused prep: x->bf16 (4096) | waT (320) | wQT (128) | wKVT (320) | wOT (2048) | bias (1)
  k_prep<<<6913, 256, 0, stream>>>(x, xbf, wdq, wdkv, waT, wuq, wQT, wukv, wKVT, wo, wOT,
                                   bdq, bdkv, biasA);

  // stage A: x @ [w_dq | w_dkv_kr] -> t0 fp32
  k_gemm_bt<0><<<dim3(3, 32), 256, 0, stream>>>(xbf, waT, biasA, t0, R_TOK, 320, 1024);
  k_stagea<<<R_TOK, 128, 0, stream>>>(t0, qnw, kvnw, pos, cq, ckv, krope);
  // stage B: q up-proj, rope+scale+scatter
  k_gemm_bt<1><<<dim3(8, 32), 256, 0, stream>>>(cq, wQT, buq, qout, R_TOK, 1024, 128);
  k_stageb<<<R_TOK, 256, 0, stream>>>(qout, pos, qst);
  // kv up-proj
  k_gemm_bt<1><<<dim3(20, 32), 256, 0, stream>>>(ckv, wKVT, bukv, kvb, R_TOK, 2560, 128);
  // attention (pair-major grid: all q-blocks of a (b,h) pair on one XCD)
  k_attn<<<dim3(16, 32), 256, 0, stream>>>(qst, kvb, krope, attnb);
  // output projection -> fp32 out
  k_gemm_bt<0><<<dim3(8, 32), 256, 0, stream>>>(attnb, wOT, bo, out, R_TOK, 1024, 2048);
}

// Round 6
// 306.149 us; speedup vs baseline: 2.4753x; 1.0159x over previous
//
#include <hip/hip_runtime.h>
#include <hip/hip_bf16.h>
#include <stdint.h>

typedef unsigned short u16;
typedef short short8 __attribute__((ext_vector_type(8)));
typedef float floatx4 __attribute__((ext_vector_type(4)));
typedef float floatx16 __attribute__((ext_vector_type(16)));

#define S_LEN 2048
#define NB 2
#define NH 8
#define R_TOK (NB * S_LEN)  // 4096

#define L2_THETA 13.287712379549449f
// attention scale folded into Q, log2 domain: (1/sqrt(128)) * log2(e)
#define QSCALE (0.08838834764831845f * 1.4426950408889634f)

__device__ inline u16 f2bf(float f) {
  union { float f; uint32_t u; } x; x.f = f;
  uint32_t r = (x.u + 0x7fffu + ((x.u >> 16) & 1u)) >> 16;
  return (u16)r;
}
__device__ inline float bf2f(u16 h) {
  union { uint32_t u; float f; } x; x.u = ((uint32_t)h) << 16;
  return x.f;
}
__device__ inline floatx4 mfma16(short8 a, short8 b, floatx4 c) {
  return __builtin_amdgcn_mfma_f32_16x16x32_bf16(a, b, c, 0, 0, 0);
}
__device__ inline floatx16 mfma32(short8 a, short8 b, floatx16 c) {
  return __builtin_amdgcn_mfma_f32_32x32x16_bf16(a, b, c, 0, 0, 0);
}
__device__ inline uint32_t pkbf(float a, float b) {
  union { __hip_bfloat162 h; uint32_t u; } c;
  c.h = __float22bfloat162_rn(make_float2(a, b));
  return c.u;
}
__device__ __forceinline__ void cp16(const void* g, const void* l) {
  __builtin_amdgcn_global_load_lds(
      (const __attribute__((address_space(1))) uint32_t*)(uintptr_t)g,
      (__attribute__((address_space(3))) uint32_t*)(uintptr_t)l, 16, 0, 0);
}

// ---------------- fused prep: x->bf16, weight transposes, bias concat ----------------
__global__ __launch_bounds__(256) void k_prep(
    const float* __restrict__ x, u16* __restrict__ xbf,
    const float* __restrict__ wdq, const float* __restrict__ wdkv, u16* __restrict__ waT,
    const float* __restrict__ wuq, u16* __restrict__ wQT,
    const float* __restrict__ wukv, u16* __restrict__ wKVT,
    const float* __restrict__ wo, u16* __restrict__ wOT,
    const float* __restrict__ bdq, const float* __restrict__ bdkv,
    float* __restrict__ biasA) {
  __shared__ u16 tile[32][33];
  const int s = blockIdx.x, tid = threadIdx.x;
  const int tx = tid & 31, ty = tid >> 5;
  if (s < 4096) {
    int i = s * 256 + tid;
    float4 v = ((const float4*)x)[i];
    ushort4 o;
    o.x = f2bf(v.x); o.y = f2bf(v.y); o.z = f2bf(v.z); o.w = f2bf(v.w);
    ((ushort4*)xbf)[i] = o;
  } else if (s < 4416) {  // waT: logical [1024][320] -> [320][1024]
    int t = s - 4096, bx = t % 10, by = t / 10;
    int c0 = bx * 32, r0 = by * 32;
#pragma unroll
    for (int i = 0; i < 4; ++i) {
      int r = r0 + ty + i * 8, c = c0 + tx;
      float v = (c < 128) ? wdq[(size_t)r * 128 + c] : wdkv[(size_t)r * 192 + (c - 128)];
      tile[ty + i * 8][tx] = f2bf(v);
    }
    __syncthreads();
#pragma unroll
    for (int i = 0; i < 4; ++i)
      waT[(size_t)(c0 + ty + i * 8) * 1024 + r0 + tx] = tile[tx][ty + i * 8];
  } else {
    const float* in; u16* out; int R, C, bx, by;
    if (s < 4544) { int t = s - 4416; in = wuq; out = wQT; R = 128; C = 1024; bx = t & 31; by = t >> 5; }
    else if (s < 4864) { int t = s - 4544; in = wukv; out = wKVT; R = 128; C = 2560; bx = t % 80; by = t / 80; }
    else if (s < 6912) { int t = s - 4864; in = wo; out = wOT; R = 2048; C = 1024; bx = t & 31; by = t >> 5; }
    else {
      if (tid < 320) biasA[tid] = (tid < 128) ? bdq[tid] : bdkv[tid - 128];
      return;
    }
    int c0 = bx * 32, r0 = by * 32;
#pragma unroll
    for (int i = 0; i < 4; ++i)
      tile[ty + i * 8][tx] = f2bf(in[(size_t)(r0 + ty + i * 8) * C + c0 + tx]);
    __syncthreads();
#pragma unroll
    for (int i = 0; i < 4; ++i)
      out[(size_t)(c0 + ty + i * 8) * R + r0 + tx] = tile[tx][ty + i * 8];
  }
}

// ---------------- 128x128-tile GEMM, B transposed [N][K], double-buffered async staging ----
template <int OUT_BF>
__global__ __launch_bounds__(256) void k_gemm_bt(const u16* __restrict__ A,
                                                 const u16* __restrict__ BT,
                                                 const float* __restrict__ bias,
                                                 void* __restrict__ Cout,
                                                 int M, int N, int K) {
  __shared__ __align__(16) u16 Alds[2][128 * 32];
  __shared__ __align__(16) u16 Blds[2][128 * 32];
  const int tid = threadIdx.x;
  const int wave = tid >> 6, lane = tid & 63;
  const int lane15 = lane & 15, quad = lane >> 4;
  const int m0 = blockIdx.y * 128, n0 = blockIdx.x * 128;
  const int mw = (wave & 1) * 64, nw = (wave >> 1) * 64;

  floatx4 acc[4][4];
#pragma unroll
  for (int a = 0; a < 4; ++a)
#pragma unroll
    for (int b = 0; b < 4; ++b) acc[a][b] = (floatx4){0.f, 0.f, 0.f, 0.f};

  const int srow = wave * 32 + (lane >> 2);
  const int scol = (lane & 3) * 8;

  auto stage = [&](int k0, int buf) {
    const u16* ga = A + (size_t)(m0 + srow) * K + k0 + scol;
    cp16(ga, Alds[buf] + srow * 32 + scol);
    cp16(ga + (size_t)16 * K, Alds[buf] + (srow + 16) * 32 + scol);
    const u16* gb = BT + (size_t)(n0 + srow) * K + k0 + scol;
    cp16(gb, Blds[buf] + srow * 32 + scol);
    cp16(gb + (size_t)16 * K, Blds[buf] + (srow + 16) * 32 + scol);
  };

  stage(0, 0);
  int cur = 0;
  for (int k0 = 0; k0 < K; k0 += 32) {
    __syncthreads();  // drains stage(k0); releases buf[cur^1]
    if (k0 + 32 < K) stage(k0 + 32, cur ^ 1);
    short8 af[4], bf[4];
#pragma unroll
    for (int im = 0; im < 4; ++im)
      af[im] = *(const short8*)&Alds[cur][(mw + im * 16 + lane15) * 32 + quad * 8];
#pragma unroll
    for (int in = 0; in < 4; ++in)
      bf[in] = *(const short8*)&Blds[cur][(nw + in * 16 + lane15) * 32 + quad * 8];
#pragma unroll
    for (int im = 0; im < 4; ++im)
#pragma unroll
      for (int in = 0; in < 4; ++in) acc[im][in] = mfma16(af[im], bf[in], acc[im][in]);
    cur ^= 1;
  }

#pragma unroll
  for (int im = 0; im < 4; ++im)
#pragma unroll
    for (int in = 0; in < 4; ++in)
#pragma unroll
      for (int r = 0; r < 4; ++r) {
        int row = m0 + mw + im * 16 + quad * 4 + r;
        int col = n0 + nw + in * 16 + lane15;
        if (col < N) {
          float v = acc[im][in][r] + bias[col];
          if (OUT_BF)
            ((u16*)Cout)[(size_t)row * N + col] = f2bf(v);
          else
            ((float*)Cout)[(size_t)row * N + col] = v;
        }
      }
}

// ---------------- stage-A epilogue: rmsnorm(cq), rmsnorm(ckv), rope(k_rope) ----------------
__global__ void k_stagea(const float* __restrict__ t0, const float* __restrict__ qnw,
                         const float* __restrict__ kvnw, const int* __restrict__ pos_ids,
                         u16* __restrict__ cq, u16* __restrict__ ckv,
                         u16* __restrict__ krope) {
  int r = blockIdx.x, tid = threadIdx.x;  // 128 threads
  const float* row = t0 + (size_t)r * 320;
  float a = row[tid];
  float b = row[128 + tid];
  float sa = a * a, sb = b * b;
#pragma unroll
  for (int d = 1; d < 64; d <<= 1) {
    sa += __shfl_xor(sa, d);
    sb += __shfl_xor(sb, d);
  }
  __shared__ float red[4];
  if ((tid & 63) == 0) { red[(tid >> 6) * 2] = sa; red[(tid >> 6) * 2 + 1] = sb; }
  __syncthreads();
  sa = red[0] + red[2];
  sb = red[1] + red[3];
  float ra = rsqrtf(sa * (1.0f / 128.0f) + 1e-8f);
  float rb = rsqrtf(sb * (1.0f / 128.0f) + 1e-8f);
  cq[(size_t)r * 128 + tid] = f2bf(qnw[tid] * a * ra);
  ckv[(size_t)r * 128 + tid] = f2bf(kvnw[tid] * b * rb);
  if (tid < 32) {
    float xe = row[256 + 2 * tid], xo = row[256 + 2 * tid + 1];
    float p = (float)pos_ids[r];
    float freq = exp2f(-(2.0f * tid / 64.0f) * L2_THETA);
    float ang = p * freq;
    float c = cosf(ang), s = sinf(ang);
    krope[(size_t)r * 64 + 2 * tid] = f2bf(xe * c - xo * s);
    krope[(size_t)r * 64 + 2 * tid + 1] = f2bf(xe * s + xo * c);
  }
}

// ---------------- stage-B epilogue: rope(q_rope) + scale + scatter ----------------
__global__ void k_stageb(const u16* __restrict__ q, const int* __restrict__ pos_ids,
                         u16* __restrict__ qstates) {
  int r = blockIdx.x, tid = threadIdx.x;  // 256 threads
  int b = r >> 11, s = r & (S_LEN - 1);
  float p = (float)pos_ids[r];
#pragma unroll
  for (int i = 0; i < 4; ++i) {
    int idx = tid + i * 256;
    int h = idx >> 7, d = idx & 127;
    float val;
    if (d < 96) {
      val = bf2f(q[(size_t)r * 1024 + h * 96 + d]);
    } else {
      int j = d - 96, pr = j >> 1;
      float xe = bf2f(q[(size_t)r * 1024 + 768 + h * 32 + 2 * pr]);
      float xo = bf2f(q[(size_t)r * 1024 + 768 + h * 32 + 2 * pr + 1]);
      float freq = exp2f(-(2.0f * pr / 32.0f) * L2_THETA);
      float ang = p * freq;
      float c = cosf(ang), sn = sinf(ang);
      val = (j & 1) ? (xe * sn + xo * c) : (xe * c - xo * sn);
    }
    qstates[((size_t)(b * NH + h) * S_LEN + s) * 128 + d] = f2bf(val * QSCALE);
  }
}

// ---------------- V transpose with PV k-permutation baked in ----------------
// vT[pair][n=256][p=2048]: vT[n][p] = V[(p&~31) + k5(p&31)][n]
// k5: u2=p5>>3 -> s=u2>>1, hi=u2&1; j=p5&7; k5 = 16s + 4hi + (j&3) + 8*(j>>2)
__global__ __launch_bounds__(256) void k_vt(const u16* __restrict__ kvb, u16* __restrict__ vT) {
  __shared__ u16 tile[32][68];
  const int nx = blockIdx.x;   // 0..3
  const int sy = blockIdx.y;   // 0..63
  const int pz = blockIdx.z;   // pair
  const int b = pz >> 3, h = pz & 7;
  const int tid = threadIdx.x;
  const int n0 = nx * 64, s0 = sy * 32;
  {
    int rr = tid >> 4, cc = (tid & 15) * 4;
#pragma unroll
    for (int i = 0; i < 2; ++i) {
      int r = rr + 16 * i;
      const u16* src = kvb + ((size_t)(b * S_LEN + s0 + r)) * 2560 + 512 + h * 256 + n0 + cc;
      ushort4 v = *(const ushort4*)src;
      tile[r][cc] = v.x; tile[r][cc + 1] = v.y; tile[r][cc + 2] = v.z; tile[r][cc + 3] = v.w;
    }
  }
  __syncthreads();
  {
    int nl = tid >> 3, a = tid & 7;
    int p5 = a * 4;
    int k5b = 16 * ((a >> 2) & 1) + 4 * ((a >> 1) & 1) + 8 * (a & 1);
#pragma unroll
    for (int i = 0; i < 2; ++i) {
      int n = nl + 32 * i;
      ushort4 o;
      o.x = tile[k5b][n]; o.y = tile[k5b + 1][n]; o.z = tile[k5b + 2][n]; o.w = tile[k5b + 3][n];
      *(ushort4*)&vT[((size_t)pz * 256 + n0 + n) * 2048 + s0 + p5] = o;
    }
  }
}

// ---------------- flash attention: 32x32x16 MFMA, fully async staging ----------------
__global__ __launch_bounds__(128) void k_attn(const u16* __restrict__ qstates,
                                              const u16* __restrict__ kv,
                                              const u16* __restrict__ krope,
                                              const u16* __restrict__ vT,
                                              u16* __restrict__ attn_out) {
  const int pair = blockIdx.x;
  const int qblk = blockIdx.y;
  const int b = pair >> 3, h = pair & 7;
  const int tid = threadIdx.x;
  const int w = tid >> 6, lane = tid & 63;
  const int l31 = lane & 31, hi = lane >> 5, l15 = lane & 15;

  __shared__ __align__(16) u16 Klds[2][64 * 128];  // 2 x 16 KB, unit-major, u' = u ^ (row&15)
  __shared__ __align__(16) u16 Vlds[256 * 64];     // 32 KB, unit u' = u ^ ((n>>3)&7)

  short8 qfrag[8];
  {
    const u16* qb =
        qstates + ((size_t)(b * NH + h) * S_LEN + qblk * 64 + w * 32 + l31) * 128 + hi * 8;
#pragma unroll
    for (int c = 0; c < 8; ++c) qfrag[c] = *(const short8*)(qb + c * 16);
  }

  floatx16 acc[8];
#pragma unroll
  for (int nt = 0; nt < 8; ++nt)
#pragma unroll
    for (int r = 0; r < 16; ++r) acc[nt][r] = 0.f;
  float m_i = -1e30f, l_i = 0.f;

  const int lr = lane >> 4;
  const u16* kp[4];
  int kstr[4];
#pragma unroll
  for (int p = 0; p < 4; ++p) {
    int row = 32 * w + 4 * p + lr;
    int u = l15 ^ ((4 * p + lr) & 15);
    const u16* base;
    int str;
    if (u < 8) { base = kv + h * 64 + u * 8; str = 2560; }
    else { base = krope + (u - 8) * 8; str = 64; }
    kp[p] = base + (size_t)(b * S_LEN + row) * str;
    kstr[p] = str;
  }
  auto issueK = [&](u16* kbuf) {
#pragma unroll
    for (int o = 0; o < 8; ++o) {
      const u16* src = kp[o & 3] + (o >= 4 ? (size_t)16 * kstr[o & 3] : (size_t)0);
      cp16(src, kbuf + ((8 * w + o) * 64 + lane) * 8);
    }
#pragma unroll
    for (int p = 0; p < 4; ++p) kp[p] += (size_t)64 * kstr[p];
  };
  const u16* vp = vT + ((size_t)pair * 256 + w * 128 + (lane >> 3)) * 2048;
  auto issueV = [&]() {
#pragma unroll
    for (int oi = 0; oi < 16; ++oi) {
      const u16* src = vp + (size_t)oi * (8 * 2048) + (((lane & 7) ^ (oi & 7)) << 3);
      cp16(src, Vlds + ((w * 128 + oi * 8) * 8 + lane) * 8);
    }
    vp += 64;
  };

  issueK(Klds[0]);
  int cur = 0;

  for (int ch = 0; ch < S_LEN / 64; ++ch) {
    __syncthreads();  // A
    issueV();
    if (ch + 1 < S_LEN / 64) issueK(Klds[cur ^ 1]);

    const u16* kb = Klds[cur];
    floatx16 st0, st1;
#pragma unroll
    for (int r = 0; r < 16; ++r) { st0[r] = 0.f; st1[r] = 0.f; }
#pragma unroll
    for (int c = 0; c < 8; ++c) {
      int up = (2 * c + hi) ^ l15;
      short8 k0 = *(const short8*)&kb[l31 * 128 + up * 8];
      short8 k1 = *(const short8*)&kb[(32 + l31) * 128 + up * 8];
      st0 = mfma32(k0, qfrag[c], st0);
      st1 = mfma32(k1, qfrag[c], st1);
    }

    float mloc = st0[0];
#pragma unroll
    for (int r = 0; r < 16; ++r) { mloc = fmaxf(mloc, st0[r]); mloc = fmaxf(mloc, st1[r]); }
    mloc = fmaxf(mloc, __shfl_xor(mloc, 32));
    float mnew = fmaxf(m_i, mloc);
    float rs = 0.f;
    union { short8 s; uint32_t d[4]; } af[4];
    {
      float pv0[16], pv1[16];
#pragma unroll
      for (int r = 0; r < 16; ++r) { pv0[r] = exp2f(st0[r] - mnew); rs += pv0[r]; }
#pragma unroll
      for (int r = 0; r < 16; ++r) { pv1[r] = exp2f(st1[r] - mnew); rs += pv1[r]; }
#pragma unroll
      for (int s = 0; s < 2; ++s)
#pragma unroll
        for (int d = 0; d < 4; ++d) {
          af[s].d[d] = pkbf(pv0[s * 8 + 2 * d], pv0[s * 8 + 2 * d + 1]);
          af[2 + s].d[d] = pkbf(pv1[s * 8 + 2 * d], pv1[s * 8 + 2 * d + 1]);
        }
    }
    rs += __shfl_xor(rs, 32);

    if (__any(mloc > m_i)) {
      float alpha = exp2f(m_i - mnew);
      l_i = l_i * alpha + rs;
      m_i = mnew;
      float al[16];
#pragma unroll
      for (int r = 0; r < 16; ++r)
        al[r] = __shfl(alpha, (r & 3) + 8 * (r >> 2) + 4 * hi, 32);
#pragma unroll
      for (int nt = 0; nt < 8; ++nt)
#pragma unroll
        for (int r = 0; r < 16; ++r) acc[nt][r] *= al[r];
    } else {
      l_i += rs;
    }

    __syncthreads();  // B: V(ch) (and K(ch+1)) drained
#pragma unroll
    for (int nt = 0; nt < 8; ++nt) {
      int n = nt * 32 + l31;
      int sw = (n >> 3) & 7;
      floatx16 o = acc[nt];
#pragma unroll
      for (int m = 0; m < 4; ++m) {
        short8 bf = *(const short8*)&Vlds[n * 64 + (((2 * m + hi) ^ sw) & 7) * 8];
        o = mfma32(af[m].s, bf, o);
      }
      acc[nt] = o;
    }
    cur ^= 1;
  }

  float rl = 1.0f / l_i;
  float linv[16];
#pragma unroll
  for (int r = 0; r < 16; ++r)
    linv[r] = __shfl(rl, (r & 3) + 8 * (r >> 2) + 4 * hi, 32);
#pragma unroll
  for (int nt = 0; nt < 8; ++nt)
#pragma unroll
    for (int r = 0; r < 16; ++r) {
      int row = qblk * 64 + w * 32 + (r & 3) + 8 * (r >> 2) + 4 * hi;
      int col = h * 256 + nt * 32 + l31;
      attn_out[((size_t)b * S_LEN + row) * 2048 + col] = f2bf(acc[nt][r] * linv[r]);
    }
}

extern "C" void kernel_launch(void* const* d_in, const int* in_sizes, int n_in,
                              void* d_out, int out_size, void* d_ws, size_t ws_size,
                              hipStream_t stream) {
  const float* x = (const float*)d_in[0];
  const int* pos = (const int*)d_in[1];
  const float* wdq = (const float*)d_in[2];
  const float* bdq = (const float*)d_in[3];
  const float* qnw = (const float*)d_in[4];
  const float* wuq = (const float*)d_in[5];
  const float* buq = (const float*)d_in[6];
  const float* wdkv = (const float*)d_in[7];
  const float* bdkv = (const float*)d_in[8];
  const float* kvnw = (const float*)d_in[9];
  const float* wukv = (const float*)d_in[10];
  const float* bukv = (const float*)d_in[11];
  const float* wo = (const float*)d_in[12];
  const float* bo = (const float*)d_in[13];
  float* out = (float*)d_out;

  char* ws = (char*)d_ws;
  size_t off = 0;
  auto alloc = [&](size_t bytes) {
    char* p = ws + off;
    off += (bytes + 255) & ~(size_t)255;
    return p;
  };
  // first three are dead by the time k_vt runs -> vT aliases them (16MB <= 21.25MB)
  u16* xbf = (u16*)alloc((size_t)R_TOK * 1024 * 2);    // dead after gemm A
  float* t0 = (float*)alloc((size_t)R_TOK * 320 * 4);  // dead after stagea
  u16* qout = (u16*)alloc((size_t)R_TOK * 1024 * 2);   // dead after stageb
  u16* vT = (u16*)d_ws;                                // alias of the three above
  u16* waT = (u16*)alloc((size_t)384 * 1024 * 2);      // padded 320->384 rows
  float* biasA = (float*)alloc(320 * 4);
  u16* wQT = (u16*)alloc((size_t)1024 * 128 * 2);
  u16* wKVT = (u16*)alloc((size_t)2560 * 128 * 2);
  u16* wOT = (u16*)alloc((size_t)1024 * 2048 * 2);
  u16* cq = (u16*)alloc((size_t)R_TOK * 128 * 2);
  u16* ckv = (u16*)alloc((size_t)R_TOK * 128 * 2);
  u16* krope = (u16*)alloc((size_t)R_TOK * 64 * 2);
  u16* qst = (u16*)alloc((size_t)R_TOK * 1024 * 2);
  u16* kvb = (u16*)alloc((size_t)R_TOK * 2560 * 2);
  u16* attnb = (u16*)alloc((size_t)R_TOK * 2048 * 2);
  (void)ws_size; (void)n_in; (void)in_sizes; (void)out_size;

  k_prep<<<6913, 256, 0, stream>>>(x, xbf, wdq, wdkv, waT, wuq, wQT, wukv, wKVT, wo, wOT,
                                   bdq, bdkv, biasA);

  // stage A: x @ [w_dq | w_dkv_kr] -> t0 fp32
  k_gemm_bt<0><<<dim3(3, 32), 256, 0, stream>>>(xbf, waT, biasA, t0, R_TOK, 320, 1024);
  k_stagea<<<R_TOK, 128, 0, stream>>>(t0, qnw, kvnw, pos, cq, ckv, krope);
  // stage B: q up-proj, rope+scale+scatter
  k_gemm_bt<1><<<dim3(8, 32), 256, 0, stream>>>(cq, wQT, buq, qout, R_TOK, 1024, 128);
  k_stageb<<<R_TOK, 256, 0, stream>>>(qout, pos, qst);
  // kv up-proj
  k_gemm_bt<1><<<dim3(20, 32), 256, 0, stream>>>(ckv, wKVT, bukv, kvb, R_TOK, 2560, 128);
  // V transpose (permuted-k layout); xbf/t0/qout dead here
  k_vt<<<dim3(4, 64, 16), 256, 0, stream>>>(kvb, vT);
  // attention (pair-major grid)
  k_attn<<<dim3(16, 32), 128, 0, stream>>>(qst, kvb, krope, vT, attnb);
  // output projection -> fp32 out
  k_gemm_bt<0><<<dim3(8, 32), 256, 0, stream>>>(attnb, wOT, bo, out, R_TOK, 1024, 2048);
}